// Round 9
// baseline (386.823 us; speedup 1.0000x reference)
//
#include <hip/hip_runtime.h>

// Problem constants: B=2, S=2048, D=2048, H=16, DH=128
#define B_  2
#define S_  2048
#define D_  2048
#define H_  16
#define DH_ 128
#define NQKV 6144              // Q|K|V concatenated column dim

typedef __bf16 bf16;
typedef __bf16 bf16x2 __attribute__((ext_vector_type(2)));
typedef __bf16 bf16x4 __attribute__((ext_vector_type(4)));
typedef __bf16 bf16x8 __attribute__((ext_vector_type(8)));
typedef float  f32x4  __attribute__((ext_vector_type(4)));

// 2^x and log2(x) via the raw ISA ops (v_exp_f32 / v_log_f32).
#define EXP2F(x) __builtin_amdgcn_exp2f(x)
#define LOG2F(x) __builtin_amdgcn_logf(x)

// DH^-0.5 * log2(e): fold softmax scale AND the exp->exp2 conversion into Q.
static constexpr float kQScale = 0.08838834764831845f * 1.4426950408889634f;

__device__ __forceinline__ void async16(const void* g, void* l) {
  __builtin_amdgcn_global_load_lds(
      (const __attribute__((address_space(1))) void*)g,
      (__attribute__((address_space(3))) void*)l, 16, 0, 0);
}

// ---------------------------------------------------------------------------
// fp32 -> bf16 conversion for all 5 tensors. Round-9 change: GRID-STRIDE with
// 2048 blocks (was 24576 one-shot blocks = 4 KB/block, the Guideline-11
// launch-overhead anti-pattern; r8 budget shows cvt+gaps ~80-110us while pure
// BW cost is ~24us). Per-unit logic identical (1024 elems/unit, block-uniform
// region select); only launch geometry changed.
// Units: x:8192 | Wq:4096 | Wk:4096 | Wv:4096 | Wo:4096  (24576 total)
__global__ void cvt_all(const float* __restrict__ x,  const float* __restrict__ wq,
                        const float* __restrict__ wk, const float* __restrict__ wv,
                        const float* __restrict__ wo,
                        bf16* __restrict__ xb, bf16* __restrict__ wqkv,
                        bf16* __restrict__ wob) {
  for (int u = blockIdx.x; u < 24576; u += gridDim.x) {
    const float* s; bf16* d; int base;
    if (u < 8192)        { s = x;  d = xb;             base = u; }
    else if (u < 12288)  { s = wq; d = wqkv;           base = u - 8192; }
    else if (u < 16384)  { s = wk; d = wqkv + 4194304; base = u - 12288; }
    else if (u < 20480)  { s = wv; d = wqkv + 8388608; base = u - 16384; }
    else                 { s = wo; d = wob;            base = u - 20480; }
    int i = (base * 256 + threadIdx.x) * 4;
    float4 v = *(const float4*)(s + i);
    bf16x4 o = {(bf16)v.x, (bf16)v.y, (bf16)v.z, (bf16)v.w};
    *(bf16x4*)(d + i) = o;
  }
}

// ---------------------------------------------------------------------------
// GEMM1 (round-0 FROZEN schedule, fused single dispatch — r8's 3-way split
// cost +38us from A-panel re-fetch, reverted): qkv = x(4096x2048) * Wqkv^T
// (6144x2048), RoPE fused for the Q,K column regions (f32 via lane-pair
// shfl), Q scaled by kQScale. Output row-major 4096x6144 bf16. BK=64.
// Schedule history: 8-phase r2=187us r3=223us, BK=32 r5=175us, 3-way split
// r8=184us — ALL regressed; do not touch schedule or launch shape.
__global__ __launch_bounds__(256, 2) void gemm_qkv(
    const bf16* __restrict__ A, const bf16* __restrict__ Bm,
    const float* __restrict__ rc, const float* __restrict__ rs,
    bf16* __restrict__ C) {
  __shared__ alignas(16) bf16 As[2][128 * 32];   // 16 KB
  __shared__ alignas(16) bf16 Bs[2][128 * 32];   // 16 KB
  const int tid = threadIdx.x;
  const int lane = tid & 63;
  const int wv = tid >> 6;
  const int quad = lane >> 4, c16 = lane & 15;
  const int wm = (wv >> 1) * 64, wn = (wv & 1) * 64;
  const int m0 = blockIdx.y * 128, n0 = blockIdx.x * 128;

  const bf16* ag = A  + (size_t)(m0 + (tid >> 2)) * D_ + (tid & 3) * 8;
  const bf16* bg = Bm + (size_t)(n0 + (tid >> 2)) * D_ + (tid & 3) * 8;
  char* asl = (char*)As + tid * 16;
  char* bsl = (char*)Bs + tid * 16;

  f32x4 acc[4][4] = {};
  for (int k0 = 0; k0 < D_; k0 += 64) {
    __syncthreads();
    async16(ag + k0,                 asl);
    async16(ag + k0 + 64 * D_,       asl + 4096);
    async16(ag + k0 + 32,            asl + 8192);
    async16(ag + k0 + 32 + 64 * D_,  asl + 12288);
    async16(bg + k0,                 bsl);
    async16(bg + k0 + 64 * D_,       bsl + 4096);
    async16(bg + k0 + 32,            bsl + 8192);
    async16(bg + k0 + 32 + 64 * D_,  bsl + 12288);
    __syncthreads();
#pragma unroll
    for (int half = 0; half < 2; ++half) {
      bf16x8 af[4], bfr[4];
#pragma unroll
      for (int i = 0; i < 4; ++i)
        af[i] = *(const bf16x8*)(As[half] + (wm + i * 16 + c16) * 32 + quad * 8);
#pragma unroll
      for (int j = 0; j < 4; ++j)
        bfr[j] = *(const bf16x8*)(Bs[half] + (wn + j * 16 + c16) * 32 + quad * 8);
#pragma unroll
      for (int i = 0; i < 4; ++i)
#pragma unroll
        for (int j = 0; j < 4; ++j)
          acc[i][j] = __builtin_amdgcn_mfma_f32_16x16x32_bf16(af[i], bfr[j], acc[i][j], 0, 0, 0);
    }
  }

  // ---- epilogue (n0 block-uniform: Q / K get RoPE, V passes through) ----
  if (n0 < 4096) {
    const float sc = (n0 < 2048) ? kQScale : 1.0f;
#pragma unroll
    for (int i = 0; i < 4; ++i) {
      const int gmi = m0 + wm + i * 16 + quad * 4;
#pragma unroll
      for (int j = 0; j < 4; ++j) {
        const int gn = n0 + wn + j * 16 + c16;
        const int d = gn & 127;
#pragma unroll
        for (int r = 0; r < 4; ++r) {
          float v = acc[i][j][r];
          float p = __shfl_xor(v, 1);          // partner (odd<->even d)
          const int gm = gmi + r;
          const int s = gm & 2047;
          const int si = s * 64 + (d >> 1);
          float c = rc[si], sn = rs[si];
          float re = (v * c - p * sn) * sc;    // valid on even lanes
          float im = (v * sn + p * c) * sc;
          if (!(lane & 1)) {
            bf16x2 o = {(bf16)re, (bf16)im};
            *(bf16x2*)(C + (size_t)gm * NQKV + gn) = o;
          }
        }
      }
    }
  } else {
#pragma unroll
    for (int i = 0; i < 4; ++i) {
      const int gmi = m0 + wm + i * 16 + quad * 4;
#pragma unroll
      for (int j = 0; j < 4; ++j) {
        const int gn = n0 + wn + j * 16 + c16;
#pragma unroll
        for (int r = 0; r < 4; ++r) {
          float v = acc[i][j][r];
          float p = __shfl_xor(v, 1);
          if (!(lane & 1)) {
            bf16x2 o = {(bf16)v, (bf16)p};
            *(bf16x2*)(C + (size_t)(gmi + r) * NQKV + gn) = o;
          }
        }
      }
    }
  }
}

// ---------------------------------------------------------------------------
// Fused per-(b,h) score + weight + V-scale kernel (v4 — best-total r6 config,
// now KNOWN < 61us from r8 diagnostic; no longer the bottleneck suspect):
// Q-hoist to VGPR; K tile [128][128] 256-B rows XOR-swizzled (chunk ^= row&7),
// conflict-free reads; double-buffered staging with counted vmcnt(8).
__global__ __launch_bounds__(256, 2) void score_wv(
    const bf16* __restrict__ qkv, bf16* __restrict__ t) {
  __shared__ alignas(16) bf16 Ks[2 * 128 * 128];  // 64 KB, 2 swizzled buffers
  __shared__ float diagL[128];
  __shared__ float lseL[128];
  const int tid = threadIdx.x;
  const int lane = tid & 63, wv = tid >> 6;
  const int quad = lane >> 4, c16 = lane & 15;
  const int wm = wv * 32;                 // each wave owns 32 distinct Q rows
  const int bh = blockIdx.y;
  const int b = bh >> 4, h = bh & 15;
  const int m0 = blockIdx.x * 128;

  // ---- Q-hoist: fragments direct global->VGPR (32 VGPRs), once ----
  bf16x8 qf[2][4];                        // [i][kt]
  {
    const bf16* qbase = qkv + (size_t)(b * 2048 + m0 + wm + c16) * NQKV
                      + h * 128 + quad * 8;
#pragma unroll
    for (int i = 0; i < 2; ++i)
#pragma unroll
      for (int kt = 0; kt < 4; ++kt)
        qf[i][kt] = *(const bf16x8*)(qbase + (size_t)(i * 16) * NQKV + kt * 32);
  }

  // ---- K staging map: thread tid -> row i*16+(tid>>4), chunk tid&15 (linear
  //      dest tid*16 + i*4096); source chunk pre-swizzled by row&7 ----
  const int srow = tid >> 4;                    // 0..15
  const int schunk = (tid & 15) ^ (srow & 7);   // involution partner
  const bf16* kg = qkv + (size_t)(b * 2048 + srow) * NQKV
                 + 2048 + h * 128 + schunk * 8;
  char* kl = (char*)Ks + tid * 16;

  float sums[8] = {0.f, 0.f, 0.f, 0.f, 0.f, 0.f, 0.f, 0.f};

  // ---- prologue: stage tile 0 into buf 0 ----
#pragma unroll
  for (int i = 0; i < 8; ++i)
    async16(kg + (size_t)(i * 16) * NQKV, kl + i * 4096);

  for (int it = 0; it < 16; ++it) {
    const int n0 = it * 128;
    // issue next tile into the other buffer, then counted wait on current
    if (it < 15) {
      char* klN = kl + (((it & 1) ^ 1) << 15);
#pragma unroll
      for (int i = 0; i < 8; ++i)
        async16(kg + (size_t)(n0 + 128 + i * 16) * NQKV, klN + i * 4096);
      asm volatile("s_waitcnt vmcnt(8)" ::: "memory");
    } else {
      asm volatile("s_waitcnt vmcnt(0)" ::: "memory");
    }
    __builtin_amdgcn_s_barrier();               // current buffer landed

    const char* kb = (const char*)Ks + ((it & 1) << 15);
    f32x4 acc[2][8] = {};
#pragma unroll
    for (int kt = 0; kt < 4; ++kt) {
#pragma unroll
      for (int j = 0; j < 8; ++j) {
        // row j*16+c16, chunk (kt*4+quad) ^ (c16&7)  [row&7 == c16&7]
        bf16x8 bb = *(const bf16x8*)(kb + (j * 16 + c16) * 256
                        + ((((kt * 4 + quad) ^ (c16 & 7))) << 4));
#pragma unroll
        for (int i = 0; i < 2; ++i)
          acc[i][j] = __builtin_amdgcn_mfma_f32_16x16x32_bf16(qf[i][kt], bb, acc[i][j], 0, 0, 0);
      }
    }
    // Diagonal tile only; compile-time acc indices, wave-uniform j guard.
    if (n0 == m0) {
#pragma unroll
      for (int i = 0; i < 2; ++i)
#pragma unroll
        for (int j = 0; j < 8; ++j)
          if (j == 2 * wv + i) {
#pragma unroll
            for (int r = 0; r < 4; ++r)
              if (c16 == quad * 4 + r)
                diagL[wm + i * 16 + quad * 4 + r] = acc[i][j][r];
          }
    }
#pragma unroll
    for (int i = 0; i < 2; ++i)
#pragma unroll
      for (int j = 0; j < 8; ++j)
#pragma unroll
        for (int r = 0; r < 4; ++r)
          sums[i * 4 + r] += EXP2F(acc[i][j][r]);

    __builtin_amdgcn_s_barrier();               // readers done before next stage
  }

#pragma unroll
  for (int tix = 0; tix < 8; ++tix) {
    float s = sums[tix];
    s += __shfl_xor(s, 1);
    s += __shfl_xor(s, 2);
    s += __shfl_xor(s, 4);
    s += __shfl_xor(s, 8);
    if (c16 == 0) {
      int i = tix >> 2, r = tix & 3;
      lseL[wm + i * 16 + quad * 4 + r] = LOG2F(s);
    }
  }

  // ---- fused V scale: t = 2^(diag - lse) * V for this block's 128 rows ----
  __syncthreads();                       // diagL/lseL visible
  const int row = tid >> 1, ch = tid & 1;
  const float w = EXP2F(diagL[row] - lseL[row]);
  const size_t grow = (size_t)(b * 2048 + m0 + row);
  const bf16* vsrc = qkv + grow * NQKV + 4096 + h * 128 + ch * 64;
  bf16* tdst = t + grow * 2048 + h * 128 + ch * 64;
#pragma unroll
  for (int c = 0; c < 8; ++c) {
    bf16x8 vv = *(const bf16x8*)(vsrc + c * 8);
    bf16x8 oo;
#pragma unroll
    for (int r = 0; r < 8; ++r) oo[r] = (bf16)((float)vv[r] * w);
    *(bf16x8*)(tdst + c * 8) = oo;
  }
}

// ---------------------------------------------------------------------------
// GEMM2: out(f32) = t(4096x2048 bf16) * Wo^T(2048x2048 bf16). BK=64, packed
// f32x2 stores via lane-pair shfl. (round-0 verified structure; UNCHANGED)
__global__ __launch_bounds__(256, 2) void gemm_out(
    const bf16* __restrict__ A, const bf16* __restrict__ Bm, float* __restrict__ C) {
  __shared__ alignas(16) bf16 As[2][128 * 32];
  __shared__ alignas(16) bf16 Bs[2][128 * 32];
  const int tid = threadIdx.x;
  const int lane = tid & 63, wv = tid >> 6;
  const int quad = lane >> 4, c16 = lane & 15;
  const int wm = (wv >> 1) * 64, wn = (wv & 1) * 64;
  const int m0 = blockIdx.y * 128, n0 = blockIdx.x * 128;

  const bf16* ag = A  + (size_t)(m0 + (tid >> 2)) * D_ + (tid & 3) * 8;
  const bf16* bg = Bm + (size_t)(n0 + (tid >> 2)) * D_ + (tid & 3) * 8;
  char* asl = (char*)As + tid * 16;
  char* bsl = (char*)Bs + tid * 16;

  f32x4 acc[4][4] = {};
  for (int k0 = 0; k0 < D_; k0 += 64) {
    __syncthreads();
    async16(ag + k0,                 asl);
    async16(ag + k0 + 64 * D_,       asl + 4096);
    async16(ag + k0 + 32,            asl + 8192);
    async16(ag + k0 + 32 + 64 * D_,  asl + 12288);
    async16(bg + k0,                 bsl);
    async16(bg + k0 + 64 * D_,       bsl + 4096);
    async16(bg + k0 + 32,            bsl + 8192);
    async16(bg + k0 + 32 + 64 * D_,  bsl + 12288);
    __syncthreads();
#pragma unroll
    for (int half = 0; half < 2; ++half) {
      bf16x8 af[4], bfr[4];
#pragma unroll
      for (int i = 0; i < 4; ++i)
        af[i] = *(const bf16x8*)(As[half] + (wm + i * 16 + c16) * 32 + quad * 8);
#pragma unroll
      for (int j = 0; j < 4; ++j)
        bfr[j] = *(const bf16x8*)(Bs[half] + (wn + j * 16 + c16) * 32 + quad * 8);
#pragma unroll
      for (int i = 0; i < 4; ++i)
#pragma unroll
        for (int j = 0; j < 4; ++j)
          acc[i][j] = __builtin_amdgcn_mfma_f32_16x16x32_bf16(af[i], bfr[j], acc[i][j], 0, 0, 0);
    }
  }
#pragma unroll
  for (int i = 0; i < 4; ++i)
#pragma unroll
    for (int j = 0; j < 4; ++j)
#pragma unroll
      for (int r = 0; r < 4; ++r) {
        float v = acc[i][j][r];
        float p = __shfl_xor(v, 1);
        if (!(lane & 1)) {
          int gm = m0 + wm + i * 16 + quad * 4 + r;
          int gn = n0 + wn + j * 16 + c16;
          float2 o = {v, p};
          *(float2*)(C + (size_t)gm * D_ + gn) = o;
        }
      }
}

// ---------------------------------------------------------------------------
extern "C" void kernel_launch(void* const* d_in, const int* in_sizes, int n_in,
                              void* d_out, int out_size, void* d_ws, size_t ws_size,
                              hipStream_t stream) {
  (void)in_sizes; (void)n_in; (void)out_size; (void)ws_size;
  const float* x  = (const float*)d_in[0];
  const float* rc = (const float*)d_in[1];
  const float* rs = (const float*)d_in[2];
  const float* Wq = (const float*)d_in[3];
  const float* Wk = (const float*)d_in[4];
  const float* Wv = (const float*)d_in[5];
  const float* Wo = (const float*)d_in[6];

  char* ws = (char*)d_ws;
  bf16* xb   = (bf16*)ws;                          // 16 MB slot (x bf16; reused as t)
  bf16* wqkv = (bf16*)(ws + 16777216);             // 24 MB (6144x2048)
  bf16* wob  = (bf16*)(ws + 16777216 + 25165824);  // 8 MB
  bf16* qkv  = (bf16*)(ws + 16777216 + 25165824 + 8388608);   // 48 MB (4096x6144)

  cvt_all<<<2048, 256, 0, stream>>>(x, Wq, Wk, Wv, Wo, xb, wqkv, wob);
  gemm_qkv<<<dim3(48, 32), 256, 0, stream>>>(xb, wqkv, rc, rs, qkv);
  score_wv<<<dim3(16, 32), 256, 0, stream>>>(qkv, xb /* t reuses xb */);
  gemm_out<<<dim3(16, 32), 256, 0, stream>>>(xb, wob, (float*)d_out);
}

// Round 10
// 371.742 us; speedup vs baseline: 1.0406x; 1.0406x over previous
//
#include <hip/hip_runtime.h>

// Problem constants: B=2, S=2048, D=2048, H=16, DH=128
#define B_  2
#define S_  2048
#define D_  2048
#define H_  16
#define DH_ 128
#define NQKV 6144              // Q|K|V concatenated column dim

typedef __bf16 bf16;
typedef __bf16 bf16x2 __attribute__((ext_vector_type(2)));
typedef __bf16 bf16x4 __attribute__((ext_vector_type(4)));
typedef __bf16 bf16x8 __attribute__((ext_vector_type(8)));
typedef float  f32x4  __attribute__((ext_vector_type(4)));

// 2^x and log2(x) via the raw ISA ops (v_exp_f32 / v_log_f32).
#define EXP2F(x) __builtin_amdgcn_exp2f(x)
#define LOG2F(x) __builtin_amdgcn_logf(x)

// DH^-0.5 * log2(e): fold softmax scale AND the exp->exp2 conversion into Q.
static constexpr float kQScale = 0.08838834764831845f * 1.4426950408889634f;

__device__ __forceinline__ void async16(const void* g, void* l) {
  __builtin_amdgcn_global_load_lds(
      (const __attribute__((address_space(1))) void*)g,
      (__attribute__((address_space(3))) void*)l, 16, 0, 0);
}

// ---------------------------------------------------------------------------
// Single fp32 -> bf16 conversion kernel (r6 one-shot form RESTORED — r9's
// 2048-block grid-stride regressed ~+18us: 12 serial branchy units/block
// killed MLP. 24576 independent 4KB blocks is the proven-fast shape.)
// Regions (blocks of 1024 elems): x:8192 | Wq:4096 | Wk:4096 | Wv:4096 | Wo:4096
__global__ void cvt_all(const float* __restrict__ x,  const float* __restrict__ wq,
                        const float* __restrict__ wk, const float* __restrict__ wv,
                        const float* __restrict__ wo,
                        bf16* __restrict__ xb, bf16* __restrict__ wqkv,
                        bf16* __restrict__ wob) {
  int bid = blockIdx.x;
  const float* s; bf16* d; int base;
  if (bid < 8192)        { s = x;  d = xb;             base = bid; }
  else if (bid < 12288)  { s = wq; d = wqkv;           base = bid - 8192; }
  else if (bid < 16384)  { s = wk; d = wqkv + 4194304; base = bid - 12288; }
  else if (bid < 20480)  { s = wv; d = wqkv + 8388608; base = bid - 16384; }
  else                   { s = wo; d = wob;            base = bid - 20480; }
  int i = (base * 256 + threadIdx.x) * 4;
  float4 v = *(const float4*)(s + i);
  bf16x4 o = {(bf16)v.x, (bf16)v.y, (bf16)v.z, (bf16)v.w};
  *(bf16x4*)(d + i) = o;
}

// ---------------------------------------------------------------------------
// GEMM1 (round-0 FROZEN schedule; round-10 adds XCD-GROUPING swizzle only):
// qkv = x(4096x2048) * Wqkv^T (6144x2048), RoPE fused for Q,K columns, Q
// scaled by kQScale. BK=64, fused single dispatch.
// r9 counter evidence: FETCH=129MB/dispatch = 8xA(16MB)+B(24MB) — the A panel
// is fetched once per XCD because default x-major grid walks one m-row across
// all 8 XCDs concurrently. Fix: 1D grid 1536, decode xcd=bid&7, slot=bid>>3,
// m_tile=xcd*4+slot/48, n_tile=slot%48 — each XCD owns 4 contiguous m-rows
// (A slice 2MB, L2-resident) and walks n within a row. Bijective 8x4x48=1536.
// Schedule history: 8-phase r2/r3, BK=32 r5, 3-way split r8 — all regressed;
// schedule stays frozen, this changes ONLY the block->tile mapping.
__global__ __launch_bounds__(256, 2) void gemm_qkv(
    const bf16* __restrict__ A, const bf16* __restrict__ Bm,
    const float* __restrict__ rc, const float* __restrict__ rs,
    bf16* __restrict__ C) {
  __shared__ alignas(16) bf16 As[2][128 * 32];   // 16 KB
  __shared__ alignas(16) bf16 Bs[2][128 * 32];   // 16 KB
  const int tid = threadIdx.x;
  const int lane = tid & 63;
  const int wv = tid >> 6;
  const int quad = lane >> 4, c16 = lane & 15;
  const int wm = (wv >> 1) * 64, wn = (wv & 1) * 64;
  // ---- XCD-grouping decode (round-10): see header comment ----
  const int bid = blockIdx.x;
  const int xcd = bid & 7, slot = bid >> 3;
  const int m0 = (xcd * 4 + slot / 48) * 128;
  const int n0 = (slot % 48) * 128;

  const bf16* ag = A  + (size_t)(m0 + (tid >> 2)) * D_ + (tid & 3) * 8;
  const bf16* bg = Bm + (size_t)(n0 + (tid >> 2)) * D_ + (tid & 3) * 8;
  char* asl = (char*)As + tid * 16;
  char* bsl = (char*)Bs + tid * 16;

  f32x4 acc[4][4] = {};
  for (int k0 = 0; k0 < D_; k0 += 64) {
    __syncthreads();
    async16(ag + k0,                 asl);
    async16(ag + k0 + 64 * D_,       asl + 4096);
    async16(ag + k0 + 32,            asl + 8192);
    async16(ag + k0 + 32 + 64 * D_,  asl + 12288);
    async16(bg + k0,                 bsl);
    async16(bg + k0 + 64 * D_,       bsl + 4096);
    async16(bg + k0 + 32,            bsl + 8192);
    async16(bg + k0 + 32 + 64 * D_,  bsl + 12288);
    __syncthreads();
#pragma unroll
    for (int half = 0; half < 2; ++half) {
      bf16x8 af[4], bfr[4];
#pragma unroll
      for (int i = 0; i < 4; ++i)
        af[i] = *(const bf16x8*)(As[half] + (wm + i * 16 + c16) * 32 + quad * 8);
#pragma unroll
      for (int j = 0; j < 4; ++j)
        bfr[j] = *(const bf16x8*)(Bs[half] + (wn + j * 16 + c16) * 32 + quad * 8);
#pragma unroll
      for (int i = 0; i < 4; ++i)
#pragma unroll
        for (int j = 0; j < 4; ++j)
          acc[i][j] = __builtin_amdgcn_mfma_f32_16x16x32_bf16(af[i], bfr[j], acc[i][j], 0, 0, 0);
    }
  }

  // ---- epilogue (n0 block-uniform: Q / K get RoPE, V passes through) ----
  if (n0 < 4096) {
    const float sc = (n0 < 2048) ? kQScale : 1.0f;
#pragma unroll
    for (int i = 0; i < 4; ++i) {
      const int gmi = m0 + wm + i * 16 + quad * 4;
#pragma unroll
      for (int j = 0; j < 4; ++j) {
        const int gn = n0 + wn + j * 16 + c16;
        const int d = gn & 127;
#pragma unroll
        for (int r = 0; r < 4; ++r) {
          float v = acc[i][j][r];
          float p = __shfl_xor(v, 1);          // partner (odd<->even d)
          const int gm = gmi + r;
          const int s = gm & 2047;
          const int si = s * 64 + (d >> 1);
          float c = rc[si], sn = rs[si];
          float re = (v * c - p * sn) * sc;    // valid on even lanes
          float im = (v * sn + p * c) * sc;
          if (!(lane & 1)) {
            bf16x2 o = {(bf16)re, (bf16)im};
            *(bf16x2*)(C + (size_t)gm * NQKV + gn) = o;
          }
        }
      }
    }
  } else {
#pragma unroll
    for (int i = 0; i < 4; ++i) {
      const int gmi = m0 + wm + i * 16 + quad * 4;
#pragma unroll
      for (int j = 0; j < 4; ++j) {
        const int gn = n0 + wn + j * 16 + c16;
#pragma unroll
        for (int r = 0; r < 4; ++r) {
          float v = acc[i][j][r];
          float p = __shfl_xor(v, 1);
          if (!(lane & 1)) {
            bf16x2 o = {(bf16)v, (bf16)p};
            *(bf16x2*)(C + (size_t)(gmi + r) * NQKV + gn) = o;
          }
        }
      }
    }
  }
}

// ---------------------------------------------------------------------------
// Fused per-(b,h) score + weight + V-scale kernel (v4 — best-total config,
// known < 61us from r8 diagnostic): Q-hoist to VGPR; K tile [128][128] 256-B
// rows XOR-swizzled (chunk ^= row&7), conflict-free reads; double-buffered
// staging with counted vmcnt(8). UNCHANGED.
__global__ __launch_bounds__(256, 2) void score_wv(
    const bf16* __restrict__ qkv, bf16* __restrict__ t) {
  __shared__ alignas(16) bf16 Ks[2 * 128 * 128];  // 64 KB, 2 swizzled buffers
  __shared__ float diagL[128];
  __shared__ float lseL[128];
  const int tid = threadIdx.x;
  const int lane = tid & 63, wv = tid >> 6;
  const int quad = lane >> 4, c16 = lane & 15;
  const int wm = wv * 32;                 // each wave owns 32 distinct Q rows
  const int bh = blockIdx.y;
  const int b = bh >> 4, h = bh & 15;
  const int m0 = blockIdx.x * 128;

  // ---- Q-hoist: fragments direct global->VGPR (32 VGPRs), once ----
  bf16x8 qf[2][4];                        // [i][kt]
  {
    const bf16* qbase = qkv + (size_t)(b * 2048 + m0 + wm + c16) * NQKV
                      + h * 128 + quad * 8;
#pragma unroll
    for (int i = 0; i < 2; ++i)
#pragma unroll
      for (int kt = 0; kt < 4; ++kt)
        qf[i][kt] = *(const bf16x8*)(qbase + (size_t)(i * 16) * NQKV + kt * 32);
  }

  // ---- K staging map: thread tid -> row i*16+(tid>>4), chunk tid&15 (linear
  //      dest tid*16 + i*4096); source chunk pre-swizzled by row&7 ----
  const int srow = tid >> 4;                    // 0..15
  const int schunk = (tid & 15) ^ (srow & 7);   // involution partner
  const bf16* kg = qkv + (size_t)(b * 2048 + srow) * NQKV
                 + 2048 + h * 128 + schunk * 8;
  char* kl = (char*)Ks + tid * 16;

  float sums[8] = {0.f, 0.f, 0.f, 0.f, 0.f, 0.f, 0.f, 0.f};

  // ---- prologue: stage tile 0 into buf 0 ----
#pragma unroll
  for (int i = 0; i < 8; ++i)
    async16(kg + (size_t)(i * 16) * NQKV, kl + i * 4096);

  for (int it = 0; it < 16; ++it) {
    const int n0 = it * 128;
    // issue next tile into the other buffer, then counted wait on current
    if (it < 15) {
      char* klN = kl + (((it & 1) ^ 1) << 15);
#pragma unroll
      for (int i = 0; i < 8; ++i)
        async16(kg + (size_t)(n0 + 128 + i * 16) * NQKV, klN + i * 4096);
      asm volatile("s_waitcnt vmcnt(8)" ::: "memory");
    } else {
      asm volatile("s_waitcnt vmcnt(0)" ::: "memory");
    }
    __builtin_amdgcn_s_barrier();               // current buffer landed

    const char* kb = (const char*)Ks + ((it & 1) << 15);
    f32x4 acc[2][8] = {};
#pragma unroll
    for (int kt = 0; kt < 4; ++kt) {
#pragma unroll
      for (int j = 0; j < 8; ++j) {
        // row j*16+c16, chunk (kt*4+quad) ^ (c16&7)  [row&7 == c16&7]
        bf16x8 bb = *(const bf16x8*)(kb + (j * 16 + c16) * 256
                        + ((((kt * 4 + quad) ^ (c16 & 7))) << 4));
#pragma unroll
        for (int i = 0; i < 2; ++i)
          acc[i][j] = __builtin_amdgcn_mfma_f32_16x16x32_bf16(qf[i][kt], bb, acc[i][j], 0, 0, 0);
      }
    }
    // Diagonal tile only; compile-time acc indices, wave-uniform j guard.
    if (n0 == m0) {
#pragma unroll
      for (int i = 0; i < 2; ++i)
#pragma unroll
        for (int j = 0; j < 8; ++j)
          if (j == 2 * wv + i) {
#pragma unroll
            for (int r = 0; r < 4; ++r)
              if (c16 == quad * 4 + r)
                diagL[wm + i * 16 + quad * 4 + r] = acc[i][j][r];
          }
    }
#pragma unroll
    for (int i = 0; i < 2; ++i)
#pragma unroll
      for (int j = 0; j < 8; ++j)
#pragma unroll
        for (int r = 0; r < 4; ++r)
          sums[i * 4 + r] += EXP2F(acc[i][j][r]);

    __builtin_amdgcn_s_barrier();               // readers done before next stage
  }

#pragma unroll
  for (int tix = 0; tix < 8; ++tix) {
    float s = sums[tix];
    s += __shfl_xor(s, 1);
    s += __shfl_xor(s, 2);
    s += __shfl_xor(s, 4);
    s += __shfl_xor(s, 8);
    if (c16 == 0) {
      int i = tix >> 2, r = tix & 3;
      lseL[wm + i * 16 + quad * 4 + r] = LOG2F(s);
    }
  }

  // ---- fused V scale: t = 2^(diag - lse) * V for this block's 128 rows ----
  __syncthreads();                       // diagL/lseL visible
  const int row = tid >> 1, ch = tid & 1;
  const float w = EXP2F(diagL[row] - lseL[row]);
  const size_t grow = (size_t)(b * 2048 + m0 + row);
  const bf16* vsrc = qkv + grow * NQKV + 4096 + h * 128 + ch * 64;
  bf16* tdst = t + grow * 2048 + h * 128 + ch * 64;
#pragma unroll
  for (int c = 0; c < 8; ++c) {
    bf16x8 vv = *(const bf16x8*)(vsrc + c * 8);
    bf16x8 oo;
#pragma unroll
    for (int r = 0; r < 8; ++r) oo[r] = (bf16)((float)vv[r] * w);
    *(bf16x8*)(tdst + c * 8) = oo;
  }
}

// ---------------------------------------------------------------------------
// GEMM2: out(f32) = t(4096x2048 bf16) * Wo^T(2048x2048 bf16). BK=64, packed
// f32x2 stores via lane-pair shfl. (round-0 verified structure; UNCHANGED)
__global__ __launch_bounds__(256, 2) void gemm_out(
    const bf16* __restrict__ A, const bf16* __restrict__ Bm, float* __restrict__ C) {
  __shared__ alignas(16) bf16 As[2][128 * 32];
  __shared__ alignas(16) bf16 Bs[2][128 * 32];
  const int tid = threadIdx.x;
  const int lane = tid & 63, wv = tid >> 6;
  const int quad = lane >> 4, c16 = lane & 15;
  const int wm = (wv >> 1) * 64, wn = (wv & 1) * 64;
  const int m0 = blockIdx.y * 128, n0 = blockIdx.x * 128;

  const bf16* ag = A  + (size_t)(m0 + (tid >> 2)) * D_ + (tid & 3) * 8;
  const bf16* bg = Bm + (size_t)(n0 + (tid >> 2)) * D_ + (tid & 3) * 8;
  char* asl = (char*)As + tid * 16;
  char* bsl = (char*)Bs + tid * 16;

  f32x4 acc[4][4] = {};
  for (int k0 = 0; k0 < D_; k0 += 64) {
    __syncthreads();
    async16(ag + k0,                 asl);
    async16(ag + k0 + 64 * D_,       asl + 4096);
    async16(ag + k0 + 32,            asl + 8192);
    async16(ag + k0 + 32 + 64 * D_,  asl + 12288);
    async16(bg + k0,                 bsl);
    async16(bg + k0 + 64 * D_,       bsl + 4096);
    async16(bg + k0 + 32,            bsl + 8192);
    async16(bg + k0 + 32 + 64 * D_,  bsl + 12288);
    __syncthreads();
#pragma unroll
    for (int half = 0; half < 2; ++half) {
      bf16x8 af[4], bfr[4];
#pragma unroll
      for (int i = 0; i < 4; ++i)
        af[i] = *(const bf16x8*)(As[half] + (wm + i * 16 + c16) * 32 + quad * 8);
#pragma unroll
      for (int j = 0; j < 4; ++j)
        bfr[j] = *(const bf16x8*)(Bs[half] + (wn + j * 16 + c16) * 32 + quad * 8);
#pragma unroll
      for (int i = 0; i < 4; ++i)
#pragma unroll
        for (int j = 0; j < 4; ++j)
          acc[i][j] = __builtin_amdgcn_mfma_f32_16x16x32_bf16(af[i], bfr[j], acc[i][j], 0, 0, 0);
    }
  }
#pragma unroll
  for (int i = 0; i < 4; ++i)
#pragma unroll
    for (int j = 0; j < 4; ++j)
#pragma unroll
      for (int r = 0; r < 4; ++r) {
        float v = acc[i][j][r];
        float p = __shfl_xor(v, 1);
        if (!(lane & 1)) {
          int gm = m0 + wm + i * 16 + quad * 4 + r;
          int gn = n0 + wn + j * 16 + c16;
          float2 o = {v, p};
          *(float2*)(C + (size_t)gm * D_ + gn) = o;
        }
      }
}

// ---------------------------------------------------------------------------
extern "C" void kernel_launch(void* const* d_in, const int* in_sizes, int n_in,
                              void* d_out, int out_size, void* d_ws, size_t ws_size,
                              hipStream_t stream) {
  (void)in_sizes; (void)n_in; (void)out_size; (void)ws_size;
  const float* x  = (const float*)d_in[0];
  const float* rc = (const float*)d_in[1];
  const float* rs = (const float*)d_in[2];
  const float* Wq = (const float*)d_in[3];
  const float* Wk = (const float*)d_in[4];
  const float* Wv = (const float*)d_in[5];
  const float* Wo = (const float*)d_in[6];

  char* ws = (char*)d_ws;
  bf16* xb   = (bf16*)ws;                          // 16 MB slot (x bf16; reused as t)
  bf16* wqkv = (bf16*)(ws + 16777216);             // 24 MB (6144x2048)
  bf16* wob  = (bf16*)(ws + 16777216 + 25165824);  // 8 MB
  bf16* qkv  = (bf16*)(ws + 16777216 + 25165824 + 8388608);   // 48 MB (4096x6144)

  cvt_all<<<24576, 256, 0, stream>>>(x, Wq, Wk, Wv, Wo, xb, wqkv, wob);
  gemm_qkv<<<1536, 256, 0, stream>>>(xb, wqkv, rc, rs, qkv);
  score_wv<<<dim3(16, 32), 256, 0, stream>>>(qkv, xb /* t reuses xb */);
  gemm_out<<<dim3(16, 32), 256, 0, stream>>>(xb, wob, (float*)d_out);
}